// Round 1
// baseline (463.026 us; speedup 1.0000x reference)
//
#include <hip/hip_runtime.h>

#define DEPTH 11
#define D 1024
#define H 32
#define OW 1024
#define B 4096
#define N_LEAVES 2048
#define N_NODES 2047
#define SMAX 8

// ---------------------------------------------------------------------------
// Kernel 1: tree descent. One wave (64 lanes) per sample. x row held in 4
// float4 registers; per level gather node plane, f64 dot (match np f64 ref on
// the hard >=0 decision), butterfly shuffle-reduce, uniform node update.
// ---------------------------------------------------------------------------
__global__ __launch_bounds__(256) void descent_kernel(
    const float* __restrict__ x, const float* __restrict__ nw,
    const float* __restrict__ nb, int* __restrict__ leaf,
    int* __restrict__ rnk, int* __restrict__ count)
{
    int lane = threadIdx.x & 63;
    int wv   = threadIdx.x >> 6;
    int samp = blockIdx.x * 4 + wv;

    const float4* xp = (const float4*)(x + (size_t)samp * D);
    float4 xf[4];
#pragma unroll
    for (int k = 0; k < 4; k++) xf[k] = xp[lane + 64 * k];

    int node = 0;
#pragma unroll
    for (int i = 0; i < DEPTH; i++) {
        const float4* wp = (const float4*)(nw + (size_t)node * D);
        double s = 0.0;
#pragma unroll
        for (int k = 0; k < 4; k++) {
            float4 wf = wp[lane + 64 * k];
            s += (double)xf[k].x * (double)wf.x;
            s += (double)xf[k].y * (double)wf.y;
            s += (double)xf[k].z * (double)wf.z;
            s += (double)xf[k].w * (double)wf.w;
        }
#pragma unroll
        for (int m = 32; m >= 1; m >>= 1) s += __shfl_xor(s, m, 64);
        double score = s + (double)nb[node];
        int choice = (score >= 0.0) ? 1 : 0;
        // (node - (2^i-1))*2 + choice + (2^(i+1)-1) == 2*node + 1 + choice
        node = 2 * node + 1 + choice;
    }
    int lf = node - N_NODES;
    if (lane == 0) {
        leaf[samp] = lf;
        rnk[samp]  = atomicAdd(&count[lf], 1);
    }
}

// ---------------------------------------------------------------------------
// Kernel 2: exclusive prefix scan over 2048 leaf counts. Single block.
// ---------------------------------------------------------------------------
__global__ __launch_bounds__(256) void scan_kernel(
    const int* __restrict__ count, int* __restrict__ offsets)
{
    __shared__ int tot[256];
    int t = threadIdx.x;
    int c[8], s = 0;
#pragma unroll
    for (int k = 0; k < 8; k++) { c[k] = count[t * 8 + k]; s += c[k]; }
    tot[t] = s;
    __syncthreads();
    for (int off = 1; off < 256; off <<= 1) {
        int v = (t >= off) ? tot[t - off] : 0;
        __syncthreads();
        tot[t] += v;
        __syncthreads();
    }
    int base = (t > 0) ? tot[t - 1] : 0;
#pragma unroll
    for (int k = 0; k < 8; k++) { offsets[t * 8 + k] = base; base += c[k]; }
}

// ---------------------------------------------------------------------------
// Kernel 3: scatter sample ids into per-leaf buckets.
// ---------------------------------------------------------------------------
__global__ __launch_bounds__(256) void scatter_kernel(
    const int* __restrict__ leaf, const int* __restrict__ rnk,
    const int* __restrict__ offsets, int* __restrict__ bucket)
{
    int i = blockIdx.x * 256 + threadIdx.x;
    bucket[offsets[leaf[i]] + rnk[i]] = i;
}

// ---------------------------------------------------------------------------
// Kernel 4: per-leaf MLP. One block (256 thr) per leaf; weights streamed once
// per leaf, amortized over all its samples (avg 2). Templated on sample count
// so accumulator indexing is compile-time (avoid scratch spill, rule #20).
// ---------------------------------------------------------------------------
template <int SS>
__device__ __forceinline__ void mlp_compute(
    int tid, const float* __restrict__ w1, const float* __restrict__ w2,
    const float* __restrict__ b1, const float* __restrict__ b2,
    float (*xs)[D], float (*part)[8][H], float (*hs)[H],
    const int* sidx, float* __restrict__ out)
{
    // ---- layer 1: h[s][j] = relu(sum_d x[s][d]*w1[d][j] + b1[j]) ----
    // 256 threads = 32 j-cols x 8 d-groups. Wave reads 256B contiguous w1.
    int j  = tid & 31;
    int dg = tid >> 5;
    float acc[SS];
#pragma unroll
    for (int s = 0; s < SS; s++) acc[s] = 0.f;
    for (int d = dg; d < D; d += 8) {
        float wvl = w1[d * H + j];
#pragma unroll
        for (int s = 0; s < SS; s++) acc[s] += xs[s][d] * wvl;  // xs: LDS broadcast
    }
#pragma unroll
    for (int s = 0; s < SS; s++) part[s][dg][j] = acc[s];
    __syncthreads();
    {
        int s2 = tid >> 5, j2 = tid & 31;
        if (s2 < SS) {
            float sum = 0.f;
#pragma unroll
            for (int g = 0; g < 8; g++) sum += part[s2][g][j2];
            sum += b1[j2];
            hs[s2][j2] = (sum > 0.f) ? sum : 0.f;
        }
    }
    __syncthreads();

    // ---- layer 2: out[s][o] = sum_j h[s][j]*w2[j][o] + b2[o] ----
    // thread covers o = 4*tid .. 4*tid+3 (float4); wave reads 1KB contiguous.
    float a0[SS], a1[SS], a2[SS], a3[SS];
#pragma unroll
    for (int s = 0; s < SS; s++) { a0[s] = a1[s] = a2[s] = a3[s] = 0.f; }
    for (int jj = 0; jj < H; jj++) {
        float4 wvl = ((const float4*)(w2 + (size_t)jj * OW))[tid];
#pragma unroll
        for (int s = 0; s < SS; s++) {
            float hv = hs[s][jj];
            a0[s] += hv * wvl.x;
            a1[s] += hv * wvl.y;
            a2[s] += hv * wvl.z;
            a3[s] += hv * wvl.w;
        }
    }
    float4 bv = ((const float4*)b2)[tid];
#pragma unroll
    for (int s = 0; s < SS; s++) {
        float4 o4;
        o4.x = a0[s] + bv.x;
        o4.y = a1[s] + bv.y;
        o4.z = a2[s] + bv.z;
        o4.w = a3[s] + bv.w;
        ((float4*)(out + (size_t)sidx[s] * OW))[tid] = o4;
    }
}

__global__ __launch_bounds__(256) void mlp_kernel(
    const float* __restrict__ x, const float* __restrict__ w1s,
    const float* __restrict__ b1s, const float* __restrict__ w2s,
    const float* __restrict__ b2s, const int* __restrict__ offsets,
    const int* __restrict__ count, const int* __restrict__ bucket,
    float* __restrict__ out)
{
    __shared__ float xs[SMAX][D];       // 32 KB
    __shared__ float part[SMAX][8][H];  // 8 KB
    __shared__ float hs[SMAX][H];       // 1 KB
    __shared__ int   sidx[SMAX];

    int l  = blockIdx.x;
    int nS = count[l];
    if (nS == 0) return;
    int base = offsets[l];
    int tid  = threadIdx.x;

    const float* w1 = w1s + (size_t)l * D * H;
    const float* w2 = w2s + (size_t)l * H * OW;
    const float* b1 = b1s + (size_t)l * H;
    const float* b2 = b2s + (size_t)l * OW;

    for (int p0 = 0; p0 < nS; p0 += SMAX) {
        int S = min(SMAX, nS - p0);
        if (tid < S) sidx[tid] = bucket[base + p0 + tid];
        __syncthreads();
        for (int s = 0; s < S; s++) {
            ((float4*)xs[s])[tid] = ((const float4*)(x + (size_t)sidx[s] * D))[tid];
        }
        __syncthreads();
        switch (S) {
            case 1: mlp_compute<1>(tid, w1, w2, b1, b2, xs, part, hs, sidx, out); break;
            case 2: mlp_compute<2>(tid, w1, w2, b1, b2, xs, part, hs, sidx, out); break;
            case 3: mlp_compute<3>(tid, w1, w2, b1, b2, xs, part, hs, sidx, out); break;
            case 4: mlp_compute<4>(tid, w1, w2, b1, b2, xs, part, hs, sidx, out); break;
            case 5: mlp_compute<5>(tid, w1, w2, b1, b2, xs, part, hs, sidx, out); break;
            case 6: mlp_compute<6>(tid, w1, w2, b1, b2, xs, part, hs, sidx, out); break;
            case 7: mlp_compute<7>(tid, w1, w2, b1, b2, xs, part, hs, sidx, out); break;
            default: mlp_compute<8>(tid, w1, w2, b1, b2, xs, part, hs, sidx, out); break;
        }
        __syncthreads();
    }
}

// ---------------------------------------------------------------------------
extern "C" void kernel_launch(void* const* d_in, const int* in_sizes, int n_in,
                              void* d_out, int out_size, void* d_ws, size_t ws_size,
                              hipStream_t stream)
{
    const float* x   = (const float*)d_in[0];
    const float* nw  = (const float*)d_in[1];
    const float* nb  = (const float*)d_in[2];
    const float* w1s = (const float*)d_in[3];
    const float* b1s = (const float*)d_in[4];
    const float* w2s = (const float*)d_in[5];
    const float* b2s = (const float*)d_in[6];
    float* out = (float*)d_out;

    int* leaf    = (int*)d_ws;
    int* rnk     = leaf + B;
    int* count   = rnk + B;
    int* offsets = count + N_LEAVES;
    int* bucket  = offsets + N_LEAVES;

    hipMemsetAsync(count, 0, N_LEAVES * sizeof(int), stream);
    descent_kernel<<<B / 4, 256, 0, stream>>>(x, nw, nb, leaf, rnk, count);
    scan_kernel<<<1, 256, 0, stream>>>(count, offsets);
    scatter_kernel<<<B / 256, 256, 0, stream>>>(leaf, rnk, offsets, bucket);
    mlp_kernel<<<N_LEAVES, 256, 0, stream>>>(x, w1s, b1s, w2s, b2s,
                                             offsets, count, bucket, out);
}

// Round 2
// 148.755 us; speedup vs baseline: 3.1127x; 3.1127x over previous
//
#include <hip/hip_runtime.h>

#define DEPTH 11
#define D 1024
#define H 32
#define OW 1024
#define B 4096
#define N_LEAVES 2048
#define N_NODES 2047
#define SMAX 4

// ---------------------------------------------------------------------------
// Kernel 1: tree descent. One wave (64 lanes) per sample. x row held in 4
// float4 registers; per level gather node plane, f64 dot (match np f64 ref on
// the hard >=0 decision), butterfly shuffle-reduce, uniform node update.
// ---------------------------------------------------------------------------
__global__ __launch_bounds__(256) void descent_kernel(
    const float* __restrict__ x, const float* __restrict__ nw,
    const float* __restrict__ nb, int* __restrict__ leaf,
    int* __restrict__ rnk, int* __restrict__ count)
{
    int lane = threadIdx.x & 63;
    int wv   = threadIdx.x >> 6;
    int samp = blockIdx.x * 4 + wv;

    const float4* xp = (const float4*)(x + (size_t)samp * D);
    float4 xf[4];
#pragma unroll
    for (int k = 0; k < 4; k++) xf[k] = xp[lane + 64 * k];

    int node = 0;
#pragma unroll
    for (int i = 0; i < DEPTH; i++) {
        const float4* wp = (const float4*)(nw + (size_t)node * D);
        double s = 0.0;
#pragma unroll
        for (int k = 0; k < 4; k++) {
            float4 wf = wp[lane + 64 * k];
            s += (double)xf[k].x * (double)wf.x;
            s += (double)xf[k].y * (double)wf.y;
            s += (double)xf[k].z * (double)wf.z;
            s += (double)xf[k].w * (double)wf.w;
        }
#pragma unroll
        for (int m = 32; m >= 1; m >>= 1) s += __shfl_xor(s, m, 64);
        double score = s + (double)nb[node];
        int choice = (score >= 0.0) ? 1 : 0;
        node = 2 * node + 1 + choice;
    }
    int lf = node - N_NODES;
    if (lane == 0) {
        leaf[samp] = lf;
        rnk[samp]  = atomicAdd(&count[lf], 1);
    }
}

// ---------------------------------------------------------------------------
// Kernel 2: exclusive prefix scan over 2048 leaf counts. Single block.
// ---------------------------------------------------------------------------
__global__ __launch_bounds__(256) void scan_kernel(
    const int* __restrict__ count, int* __restrict__ offsets)
{
    __shared__ int tot[256];
    int t = threadIdx.x;
    int c[8], s = 0;
#pragma unroll
    for (int k = 0; k < 8; k++) { c[k] = count[t * 8 + k]; s += c[k]; }
    tot[t] = s;
    __syncthreads();
    for (int off = 1; off < 256; off <<= 1) {
        int v = (t >= off) ? tot[t - off] : 0;
        __syncthreads();
        tot[t] += v;
        __syncthreads();
    }
    int base = (t > 0) ? tot[t - 1] : 0;
#pragma unroll
    for (int k = 0; k < 8; k++) { offsets[t * 8 + k] = base; base += c[k]; }
}

// ---------------------------------------------------------------------------
// Kernel 3: scatter sample ids into per-leaf buckets.
// ---------------------------------------------------------------------------
__global__ __launch_bounds__(256) void scatter_kernel(
    const int* __restrict__ leaf, const int* __restrict__ rnk,
    const int* __restrict__ offsets, int* __restrict__ bucket)
{
    int i = blockIdx.x * 256 + threadIdx.x;
    bucket[offsets[leaf[i]] + rnk[i]] = i;
}

// ---------------------------------------------------------------------------
// Kernel 4: per-leaf MLP, float4-everywhere version.
// Layer 1: thread (dg=tid>>3, jq=tid&7) owns rows d=dg+32k, cols 4jq..4jq+3.
//   Wave reads 1 KB contiguous w1 per iteration (8 rows x 128 B).
//   Reduce over the 8 dg's within a wave via shfl_xor(8,16,32), then over the
//   4 waves via a tiny LDS buffer.
// Layer 2: thread owns out cols 4*tid..4*tid+3; 32 independent float4 loads.
// ---------------------------------------------------------------------------
template <int SS>
__device__ __forceinline__ void mlp_compute(
    int tid, const float* __restrict__ w1, const float* __restrict__ w2,
    const float* __restrict__ b1, const float* __restrict__ b2,
    float (*xs)[D], float (*pl1)[32][SMAX], float (*hs)[H],
    const int* sidx, float* __restrict__ out)
{
    const int lane = tid & 63, wave = tid >> 6;
    const int jq = tid & 7, dg = tid >> 3;
    const float4* w1v = (const float4*)w1;

    float4 acc[SS];
#pragma unroll
    for (int s = 0; s < SS; s++) acc[s] = make_float4(0.f, 0.f, 0.f, 0.f);

#pragma unroll 8
    for (int k = 0; k < 32; k++) {
        int d = dg + (k << 5);
        float4 w = w1v[(d << 3) + jq];
#pragma unroll
        for (int s = 0; s < SS; s++) {
            float xv = xs[s][d];
            acc[s].x += xv * w.x;
            acc[s].y += xv * w.y;
            acc[s].z += xv * w.z;
            acc[s].w += xv * w.w;
        }
    }
    // reduce across the 8 dg's within this wave (tid bits 3..5)
#pragma unroll
    for (int m = 8; m <= 32; m <<= 1)
#pragma unroll
        for (int s = 0; s < SS; s++) {
            acc[s].x += __shfl_xor(acc[s].x, m, 64);
            acc[s].y += __shfl_xor(acc[s].y, m, 64);
            acc[s].z += __shfl_xor(acc[s].z, m, 64);
            acc[s].w += __shfl_xor(acc[s].w, m, 64);
        }
    if (lane < 8) {
#pragma unroll
        for (int s = 0; s < SS; s++) {
            pl1[wave][jq * 4 + 0][s] = acc[s].x;
            pl1[wave][jq * 4 + 1][s] = acc[s].y;
            pl1[wave][jq * 4 + 2][s] = acc[s].z;
            pl1[wave][jq * 4 + 3][s] = acc[s].w;
        }
    }
    __syncthreads();
    if (tid < 32 * SS) {
        int s2 = tid >> 5, j2 = tid & 31;
        float sum = pl1[0][j2][s2] + pl1[1][j2][s2] + pl1[2][j2][s2] +
                    pl1[3][j2][s2] + b1[j2];
        hs[s2][j2] = fmaxf(sum, 0.f);
    }
    __syncthreads();

    // ---- layer 2 ----
    const float4* w2v = (const float4*)w2;
    float4 o[SS];
#pragma unroll
    for (int s = 0; s < SS; s++) o[s] = make_float4(0.f, 0.f, 0.f, 0.f);
#pragma unroll 8
    for (int jj = 0; jj < H; jj++) {
        float4 w = w2v[(jj << 8) + tid];
#pragma unroll
        for (int s = 0; s < SS; s++) {
            float hv = hs[s][jj];
            o[s].x += hv * w.x;
            o[s].y += hv * w.y;
            o[s].z += hv * w.z;
            o[s].w += hv * w.w;
        }
    }
    float4 bv = ((const float4*)b2)[tid];
#pragma unroll
    for (int s = 0; s < SS; s++) {
        float4 o4;
        o4.x = o[s].x + bv.x;
        o4.y = o[s].y + bv.y;
        o4.z = o[s].z + bv.z;
        o4.w = o[s].w + bv.w;
        ((float4*)(out + (size_t)sidx[s] * OW))[tid] = o4;
    }
}

__global__ __launch_bounds__(256) void mlp_kernel(
    const float* __restrict__ x, const float* __restrict__ w1s,
    const float* __restrict__ b1s, const float* __restrict__ w2s,
    const float* __restrict__ b2s, const int* __restrict__ offsets,
    const int* __restrict__ count, const int* __restrict__ bucket,
    float* __restrict__ out)
{
    __shared__ float xs[SMAX][D];          // 16 KB
    __shared__ float pl1[4][32][SMAX];     // 2 KB
    __shared__ float hs[SMAX][H];          // 0.5 KB
    __shared__ int   sidx[SMAX];

    int l  = blockIdx.x;
    int nS = count[l];
    if (nS == 0) return;
    int base = offsets[l];
    int tid  = threadIdx.x;

    const float* w1 = w1s + (size_t)l * D * H;
    const float* w2 = w2s + (size_t)l * H * OW;
    const float* b1 = b1s + (size_t)l * H;
    const float* b2 = b2s + (size_t)l * OW;

    for (int p0 = 0; p0 < nS; p0 += SMAX) {
        int S = min(SMAX, nS - p0);
        if (tid < S) sidx[tid] = bucket[base + p0 + tid];
        __syncthreads();
        for (int s = 0; s < S; s++) {
            ((float4*)xs[s])[tid] = ((const float4*)(x + (size_t)sidx[s] * D))[tid];
        }
        __syncthreads();
        switch (S) {
            case 1: mlp_compute<1>(tid, w1, w2, b1, b2, xs, pl1, hs, sidx, out); break;
            case 2: mlp_compute<2>(tid, w1, w2, b1, b2, xs, pl1, hs, sidx, out); break;
            case 3: mlp_compute<3>(tid, w1, w2, b1, b2, xs, pl1, hs, sidx, out); break;
            default: mlp_compute<4>(tid, w1, w2, b1, b2, xs, pl1, hs, sidx, out); break;
        }
        __syncthreads();
    }
}

// ---------------------------------------------------------------------------
extern "C" void kernel_launch(void* const* d_in, const int* in_sizes, int n_in,
                              void* d_out, int out_size, void* d_ws, size_t ws_size,
                              hipStream_t stream)
{
    const float* x   = (const float*)d_in[0];
    const float* nw  = (const float*)d_in[1];
    const float* nb  = (const float*)d_in[2];
    const float* w1s = (const float*)d_in[3];
    const float* b1s = (const float*)d_in[4];
    const float* w2s = (const float*)d_in[5];
    const float* b2s = (const float*)d_in[6];
    float* out = (float*)d_out;

    int* leaf    = (int*)d_ws;
    int* rnk     = leaf + B;
    int* count   = rnk + B;
    int* offsets = count + N_LEAVES;
    int* bucket  = offsets + N_LEAVES;

    hipMemsetAsync(count, 0, N_LEAVES * sizeof(int), stream);
    descent_kernel<<<B / 4, 256, 0, stream>>>(x, nw, nb, leaf, rnk, count);
    scan_kernel<<<1, 256, 0, stream>>>(count, offsets);
    scatter_kernel<<<B / 256, 256, 0, stream>>>(leaf, rnk, offsets, bucket);
    mlp_kernel<<<N_LEAVES, 256, 0, stream>>>(x, w1s, b1s, w2s, b2s,
                                             offsets, count, bucket, out);
}

// Round 3
// 143.304 us; speedup vs baseline: 3.2311x; 1.0380x over previous
//
#include <hip/hip_runtime.h>

#define DEPTH 11
#define D 1024
#define H 32
#define OW 1024
#define B 4096
#define N_LEAVES 2048
#define N_NODES 2047
#define SMAX 4
#define MAX_ITEMS 3072

// ---------------------------------------------------------------------------
// Kernel 1: tree descent. One wave (64 lanes) per sample. x row held in 4
// float4 registers; per level gather node plane, f64 dot (match np f64 ref on
// the hard >=0 decision), butterfly shuffle-reduce, uniform node update.
// ---------------------------------------------------------------------------
__global__ __launch_bounds__(256) void descent_kernel(
    const float* __restrict__ x, const float* __restrict__ nw,
    const float* __restrict__ nb, int* __restrict__ leaf,
    int* __restrict__ rnk, int* __restrict__ count)
{
    int lane = threadIdx.x & 63;
    int wv   = threadIdx.x >> 6;
    int samp = blockIdx.x * 4 + wv;

    const float4* xp = (const float4*)(x + (size_t)samp * D);
    float4 xf[4];
#pragma unroll
    for (int k = 0; k < 4; k++) xf[k] = xp[lane + 64 * k];

    int node = 0;
#pragma unroll
    for (int i = 0; i < DEPTH; i++) {
        const float4* wp = (const float4*)(nw + (size_t)node * D);
        double s = 0.0;
#pragma unroll
        for (int k = 0; k < 4; k++) {
            float4 wf = wp[lane + 64 * k];
            s += (double)xf[k].x * (double)wf.x;
            s += (double)xf[k].y * (double)wf.y;
            s += (double)xf[k].z * (double)wf.z;
            s += (double)xf[k].w * (double)wf.w;
        }
#pragma unroll
        for (int m = 32; m >= 1; m >>= 1) s += __shfl_xor(s, m, 64);
        double score = s + (double)nb[node];
        int choice = (score >= 0.0) ? 1 : 0;
        node = 2 * node + 1 + choice;
    }
    int lf = node - N_NODES;
    if (lane == 0) {
        leaf[samp] = lf;
        rnk[samp]  = atomicAdd(&count[lf], 1);
    }
}

// ---------------------------------------------------------------------------
// Kernel 2: exclusive prefix scan over 2048 leaf counts. Single block.
// ---------------------------------------------------------------------------
__global__ __launch_bounds__(256) void scan_kernel(
    const int* __restrict__ count, int* __restrict__ offsets)
{
    __shared__ int tot[256];
    int t = threadIdx.x;
    int c[8], s = 0;
#pragma unroll
    for (int k = 0; k < 8; k++) { c[k] = count[t * 8 + k]; s += c[k]; }
    tot[t] = s;
    __syncthreads();
    for (int off = 1; off < 256; off <<= 1) {
        int v = (t >= off) ? tot[t - off] : 0;
        __syncthreads();
        tot[t] += v;
        __syncthreads();
    }
    int base = (t > 0) ? tot[t - 1] : 0;
#pragma unroll
    for (int k = 0; k < 8; k++) { offsets[t * 8 + k] = base; base += c[k]; }
}

// ---------------------------------------------------------------------------
// Kernel 3: scatter sample ids into per-leaf buckets.
// ---------------------------------------------------------------------------
__global__ __launch_bounds__(256) void scatter_kernel(
    const int* __restrict__ leaf, const int* __restrict__ rnk,
    const int* __restrict__ offsets, int* __restrict__ bucket)
{
    int i = blockIdx.x * 256 + threadIdx.x;
    bucket[offsets[leaf[i]] + rnk[i]] = i;
}

// ---------------------------------------------------------------------------
// Kernel 3b: build work items of <=SMAX samples each. Heavy leaves become
// multiple parallel items (kills the serial second-pass tail).
// item = leaf | (start << 11).
// ---------------------------------------------------------------------------
__global__ __launch_bounds__(256) void build_items_kernel(
    const int* __restrict__ count, int* __restrict__ items,
    int* __restrict__ nitems)
{
    int l = blockIdx.x * 256 + threadIdx.x;
    int c = count[l];
    if (c > 0) {
        int k = (c + SMAX - 1) / SMAX;
        int base = atomicAdd(nitems, k);
        for (int i = 0; i < k; i++)
            items[base + i] = l | ((i * SMAX) << 11);
    }
}

// ---------------------------------------------------------------------------
// Kernel 4: per-leaf-item MLP, float4-everywhere.
// Layer 1: thread (dg=tid>>3, jq=tid&7) owns rows d=dg+32k, cols 4jq..4jq+3.
//   Wave reads 1 KB contiguous w1 per iteration; shfl_xor reduce over dg,
//   then LDS reduce over the 4 waves.
// Layer 2: thread owns out cols 4*tid..4*tid+3; 32 independent float4 loads.
// VGPR budget: must stay <=64 for 8 waves/SIMD (launch_bounds pins it).
// ---------------------------------------------------------------------------
template <int SS>
__device__ __forceinline__ void mlp_compute(
    int tid, const float* __restrict__ w1, const float* __restrict__ w2,
    const float* __restrict__ b1, const float* __restrict__ b2,
    float (*xs)[D], float (*pl1)[32][SMAX], float (*hs)[H],
    const int* sidx, float* __restrict__ out)
{
    const int lane = tid & 63, wave = tid >> 6;
    const int jq = tid & 7, dg = tid >> 3;
    const float4* w1v = (const float4*)w1;

    float4 acc[SS];
#pragma unroll
    for (int s = 0; s < SS; s++) acc[s] = make_float4(0.f, 0.f, 0.f, 0.f);

#pragma unroll 8
    for (int k = 0; k < 32; k++) {
        int d = dg + (k << 5);
        float4 w = w1v[(d << 3) + jq];
#pragma unroll
        for (int s = 0; s < SS; s++) {
            float xv = xs[s][d];
            acc[s].x += xv * w.x;
            acc[s].y += xv * w.y;
            acc[s].z += xv * w.z;
            acc[s].w += xv * w.w;
        }
    }
#pragma unroll
    for (int m = 8; m <= 32; m <<= 1)
#pragma unroll
        for (int s = 0; s < SS; s++) {
            acc[s].x += __shfl_xor(acc[s].x, m, 64);
            acc[s].y += __shfl_xor(acc[s].y, m, 64);
            acc[s].z += __shfl_xor(acc[s].z, m, 64);
            acc[s].w += __shfl_xor(acc[s].w, m, 64);
        }
    if (lane < 8) {
#pragma unroll
        for (int s = 0; s < SS; s++) {
            pl1[wave][jq * 4 + 0][s] = acc[s].x;
            pl1[wave][jq * 4 + 1][s] = acc[s].y;
            pl1[wave][jq * 4 + 2][s] = acc[s].z;
            pl1[wave][jq * 4 + 3][s] = acc[s].w;
        }
    }
    __syncthreads();
    if (tid < 32 * SS) {
        int s2 = tid >> 5, j2 = tid & 31;
        float sum = pl1[0][j2][s2] + pl1[1][j2][s2] + pl1[2][j2][s2] +
                    pl1[3][j2][s2] + b1[j2];
        hs[s2][j2] = fmaxf(sum, 0.f);
    }
    __syncthreads();

    const float4* w2v = (const float4*)w2;
    float4 o[SS];
#pragma unroll
    for (int s = 0; s < SS; s++) o[s] = make_float4(0.f, 0.f, 0.f, 0.f);
#pragma unroll 8
    for (int jj = 0; jj < H; jj++) {
        float4 w = w2v[(jj << 8) + tid];
#pragma unroll
        for (int s = 0; s < SS; s++) {
            float hv = hs[s][jj];
            o[s].x += hv * w.x;
            o[s].y += hv * w.y;
            o[s].z += hv * w.z;
            o[s].w += hv * w.w;
        }
    }
    float4 bv = ((const float4*)b2)[tid];
#pragma unroll
    for (int s = 0; s < SS; s++) {
        float4 o4;
        o4.x = o[s].x + bv.x;
        o4.y = o[s].y + bv.y;
        o4.z = o[s].z + bv.z;
        o4.w = o[s].w + bv.w;
        ((float4*)(out + (size_t)sidx[s] * OW))[tid] = o4;
    }
}

__global__ __launch_bounds__(256, 8) void mlp_kernel(
    const float* __restrict__ x, const float* __restrict__ w1s,
    const float* __restrict__ b1s, const float* __restrict__ w2s,
    const float* __restrict__ b2s, const int* __restrict__ offsets,
    const int* __restrict__ count, const int* __restrict__ bucket,
    const int* __restrict__ items, const int* __restrict__ nitems,
    float* __restrict__ out)
{
    __shared__ float xs[SMAX][D];          // 16 KB
    __shared__ float pl1[4][32][SMAX];     // 2 KB
    __shared__ float hs[SMAX][H];          // 0.5 KB
    __shared__ int   sidx[SMAX];

    if ((int)blockIdx.x >= nitems[0]) return;
    int item  = items[blockIdx.x];
    int l     = item & (N_LEAVES - 1);
    int start = item >> 11;
    int S     = min(SMAX, count[l] - start);
    int base  = offsets[l] + start;
    int tid   = threadIdx.x;

    const float* w1 = w1s + (size_t)l * D * H;
    const float* w2 = w2s + (size_t)l * H * OW;
    const float* b1 = b1s + (size_t)l * H;
    const float* b2 = b2s + (size_t)l * OW;

    if (tid < S) sidx[tid] = bucket[base + tid];
    __syncthreads();
    for (int s = 0; s < S; s++) {
        ((float4*)xs[s])[tid] = ((const float4*)(x + (size_t)sidx[s] * D))[tid];
    }
    __syncthreads();
    switch (S) {
        case 1: mlp_compute<1>(tid, w1, w2, b1, b2, xs, pl1, hs, sidx, out); break;
        case 2: mlp_compute<2>(tid, w1, w2, b1, b2, xs, pl1, hs, sidx, out); break;
        case 3: mlp_compute<3>(tid, w1, w2, b1, b2, xs, pl1, hs, sidx, out); break;
        default: mlp_compute<4>(tid, w1, w2, b1, b2, xs, pl1, hs, sidx, out); break;
    }
}

// ---------------------------------------------------------------------------
extern "C" void kernel_launch(void* const* d_in, const int* in_sizes, int n_in,
                              void* d_out, int out_size, void* d_ws, size_t ws_size,
                              hipStream_t stream)
{
    const float* x   = (const float*)d_in[0];
    const float* nw  = (const float*)d_in[1];
    const float* nb  = (const float*)d_in[2];
    const float* w1s = (const float*)d_in[3];
    const float* b1s = (const float*)d_in[4];
    const float* w2s = (const float*)d_in[5];
    const float* b2s = (const float*)d_in[6];
    float* out = (float*)d_out;

    int* leaf    = (int*)d_ws;
    int* rnk     = leaf + B;
    int* count   = rnk + B;
    int* offsets = count + N_LEAVES;
    int* bucket  = offsets + N_LEAVES;
    int* items   = bucket + B;
    int* nitems  = items + MAX_ITEMS;

    hipMemsetAsync(count, 0, N_LEAVES * sizeof(int), stream);
    hipMemsetAsync(nitems, 0, sizeof(int), stream);
    descent_kernel<<<B / 4, 256, 0, stream>>>(x, nw, nb, leaf, rnk, count);
    scan_kernel<<<1, 256, 0, stream>>>(count, offsets);
    scatter_kernel<<<B / 256, 256, 0, stream>>>(leaf, rnk, offsets, bucket);
    build_items_kernel<<<N_LEAVES / 256, 256, 0, stream>>>(count, items, nitems);
    mlp_kernel<<<MAX_ITEMS, 256, 0, stream>>>(x, w1s, b1s, w2s, b2s,
                                              offsets, count, bucket,
                                              items, nitems, out);
}